// Round 8
// baseline (652.731 us; speedup 1.0000x reference)
//
#include <hip/hip_runtime.h>
#include <math.h>

#define B_ 8
#define L_ 4096
#define D_ 512
#define U_ 41      // int(5 * ln(4097)) = 41
#define NSL 32

static constexpr float SCALE = 0.044194173824159216f;  // 512^-0.5

typedef __attribute__((ext_vector_type(8))) short bf16x8;
typedef __attribute__((ext_vector_type(4))) float f32x4;
typedef unsigned int uint;

// ======================= sums =======================

__global__ __launch_bounds__(512) void kSumsV4(const float* __restrict__ k,
                                               const float* __restrict__ v,
                                               float* __restrict__ partk,
                                               float* __restrict__ partv) {
  const int s = blockIdx.x;            // 0..31
  const int b = blockIdx.y;
  const int rg = threadIdx.x >> 7;     // 0..3
  const int dc = threadIdx.x & 127;    // float4 column
  const int row0 = s * 128 + rg * 32;
  const float* kp = k + ((size_t)(b * L_ + row0)) * D_ + dc * 4;
  const float* vp = v + ((size_t)(b * L_ + row0)) * D_ + dc * 4;
  float4 ks = make_float4(0.f, 0.f, 0.f, 0.f);
  float4 vs = make_float4(0.f, 0.f, 0.f, 0.f);
  for (int l = 0; l < 32; ++l) {
    float4 t = *(const float4*)(kp + (size_t)l * D_);
    float4 u = *(const float4*)(vp + (size_t)l * D_);
    ks.x += t.x; ks.y += t.y; ks.z += t.z; ks.w += t.w;
    vs.x += u.x; vs.y += u.y; vs.z += u.z; vs.w += u.w;
  }
  const int p = (b * NSL + s) * 4 + rg;
  *(float4*)(partk + (size_t)p * D_ + dc * 4) = ks;
  *(float4*)(partv + (size_t)p * D_ + dc * 4) = vs;
}

__global__ __launch_bounds__(512) void kSums2V(const float* __restrict__ partk,
                                               const float* __restrict__ partv,
                                               float* __restrict__ ksum,
                                               float* __restrict__ vmean) {
  const int b = blockIdx.x;
  const int d = threadIdx.x;
  float ks = 0.f, vs = 0.f;
  for (int p = 0; p < 128; ++p) {
    ks += partk[((size_t)(b * 128 + p)) * D_ + d];
    vs += partv[((size_t)(b * 128 + p)) * D_ + d];
  }
  ksum[b * D_ + d] = ks;
  vmean[b * D_ + d] = vs * (1.f / L_);
}

// fallback-path originals
__global__ __launch_bounds__(512) void kSums1(const float* __restrict__ k,
                                              const float* __restrict__ v,
                                              float* __restrict__ partk,
                                              float* __restrict__ partv) {
  const int s = blockIdx.x;
  const int b = blockIdx.y;
  const int d = threadIdx.x;
  const int rows = L_ / NSL;
  const size_t base = ((size_t)b * L_ + (size_t)s * rows) * D_ + d;
  float ks = 0.f, vs = 0.f;
  for (int l = 0; l < rows; ++l) {
    ks += k[base + (size_t)l * D_];
    vs += v[base + (size_t)l * D_];
  }
  partk[(b * NSL + s) * D_ + d] = ks;
  partv[(b * NSL + s) * D_ + d] = vs;
}

__global__ __launch_bounds__(512) void kSums2(const float* __restrict__ partk,
                                              const float* __restrict__ partv,
                                              float* __restrict__ ksum,
                                              float* __restrict__ vmean) {
  const int b = blockIdx.x;
  const int d = threadIdx.x;
  float ks = 0.f, vs = 0.f;
  for (int s = 0; s < NSL; ++s) {
    ks += partk[(b * NSL + s) * D_ + d];
    vs += partv[(b * NSL + s) * D_ + d];
  }
  ksum[b * D_ + d] = ks;
  vmean[b * D_ + d] = vs * (1.f / L_);
}

__global__ __launch_bounds__(256) void kMeanM(const float* __restrict__ q,
                                              const float* __restrict__ ksum,
                                              const float* __restrict__ pmax,
                                              float* __restrict__ M) {
  __shared__ float ks[D_];
  const int gid = blockIdx.x * 256 + threadIdx.x;
  const int b = gid >> 12;
  for (int i = threadIdx.x; i < D_; i += 256) ks[i] = ksum[b * D_ + i];
  __syncthreads();
  const float* qp = q + (size_t)gid * D_;
  float acc = 0.f;
  for (int i = 0; i < D_; i += 4) {
    float4 t = *(const float4*)(qp + i);
    acc += t.x * ks[i] + t.y * ks[i + 1] + t.z * ks[i + 2] + t.w * ks[i + 3];
  }
  const float rowmax = fmaxf(pmax[gid], pmax[B_ * L_ + gid]);
  M[gid] = SCALE * (rowmax - acc * (1.f / L_));
}

// fallback top-41 (reads M)
__global__ __launch_bounds__(256) void kTopK3(const float* __restrict__ M,
                                              int* __restrict__ topidx) {
  __shared__ float wv[2][4];
  __shared__ int wi[2][4];
  const int b = blockIdx.x;
  const int tid = threadIdx.x;
  const int wave = tid >> 6, lane = tid & 63;
  float v[16];
#pragma unroll
  for (int j = 0; j < 16; ++j) v[j] = M[b * L_ + tid + j * 256];
  float bv = v[0];
  int bj = 0;
#pragma unroll
  for (int j = 1; j < 16; ++j)
    if (v[j] > bv) { bv = v[j]; bj = j; }
  int bi = tid + bj * 256;

  for (int it = 0; it < U_; ++it) {
    float rv = bv;
    int ri = bi;
#pragma unroll
    for (int off = 1; off < 64; off <<= 1) {
      float ov = __shfl_xor(rv, off);
      int oi = __shfl_xor(ri, off);
      if (ov > rv || (ov == rv && oi < ri)) { rv = ov; ri = oi; }
    }
    const int par = it & 1;
    if (lane == 0) { wv[par][wave] = rv; wi[par][wave] = ri; }
    __syncthreads();
    float gv = wv[par][0];
    int gi = wi[par][0];
#pragma unroll
    for (int w = 1; w < 4; ++w) {
      float ov = wv[par][w];
      int oi = wi[par][w];
      if (ov > gv || (ov == gv && oi < gi)) { gv = ov; gi = oi; }
    }
    if (tid == 0) topidx[b * U_ + it] = gi;
    if (gi == bi) {
      const int jb = gi >> 8;
#pragma unroll
      for (int j = 0; j < 16; ++j)
        if (j == jb) v[j] = -3.4e38f;
      bv = v[0];
      bj = 0;
#pragma unroll
      for (int j = 1; j < 16; ++j)
        if (v[j] > bv) { bv = v[j]; bj = j; }
      bi = tid + bj * 256;
    }
  }
}

// fast-path top-41: single wave per batch, zero barriers, M on the fly
__global__ __launch_bounds__(64) void kTopK4(const float* __restrict__ pmax,
                                             const float* __restrict__ qdot,
                                             int* __restrict__ topidx) {
  const int b = blockIdx.x;
  const int lane = threadIdx.x;
  float v[64];
#pragma unroll
  for (int j = 0; j < 64; ++j) {
    const int gid = b * L_ + lane + j * 64;
    v[j] = SCALE * (fmaxf(pmax[gid], pmax[B_ * L_ + gid]) - qdot[gid] * (1.f / L_));
  }
  float bv = v[0];
  int bj = 0;
#pragma unroll
  for (int j = 1; j < 64; ++j)
    if (v[j] > bv) { bv = v[j]; bj = j; }
  int bi = lane + bj * 64;

  for (int it = 0; it < U_; ++it) {
    float rv = bv;
    int ri = bi;
#pragma unroll
    for (int off = 1; off < 64; off <<= 1) {
      float ov = __shfl_xor(rv, off);
      int oi = __shfl_xor(ri, off);
      if (ov > rv || (ov == rv && oi < ri)) { rv = ov; ri = oi; }
    }
    if (lane == 0) topidx[b * U_ + it] = ri;
    if (ri == bi) {
#pragma unroll
      for (int j = 0; j < 64; ++j)
        if (j == bj) v[j] = -3.4e38f;
      bv = v[0];
      bj = 0;
#pragma unroll
      for (int j = 1; j < 64; ++j)
        if (v[j] > bv) { bv = v[j]; bj = j; }
      bi = lane + bj * 64;
    }
  }
}

__global__ __launch_bounds__(256) void kFill(const float* __restrict__ vmean,
                                             float* __restrict__ out) {
  const int g = blockIdx.x * 256 + threadIdx.x;
  const int d4 = g & 127;
  const int bl = g >> 7;
  const int b = bl >> 12;
  ((float4*)out)[g] = ((const float4*)vmean)[b * 128 + d4];
}

// ======================= bf16 split helpers =======================
__device__ inline uint bf16_rne_bits(float x) {
  uint u = __builtin_bit_cast(uint, x);
  return (u + 0x7FFFu + ((u >> 16) & 1u)) >> 16;
}
__device__ inline float bits_to_f32(uint hi16) {
  return __builtin_bit_cast(float, hi16 << 16);
}

// ======================= fast path: pre-convert (BK=32 layout) =======================
// layout: [b][rt:32][dsi32:16][row:128][64B]; byte-in-row = 16*(c ^ ((row>>1)&3))
// (c = which 8-float chunk of the 32-dim slice; swizzle is conflict-free for the
//  per-16-lane-group b128 frag reads: each 8-bank cluster hit exactly 2x)
__global__ __launch_bounds__(256) void kConvert(const float* __restrict__ src,
                                                unsigned char* __restrict__ dhi,
                                                unsigned char* __restrict__ dlo) {
  const int cid = blockIdx.x * 256 + threadIdx.x;   // 2^21 total
  const int c = cid & 3;
  const int row = (cid >> 2) & 127;
  const int dsi = (cid >> 9) & 15;
  const int rt = (cid >> 13) & 31;
  const int b = cid >> 18;
  const int l = rt * 128 + row;
  const int d = dsi * 32 + c * 8;
  const float* sp = src + ((size_t)(b * L_ + l) * D_ + d);
  float x[8];
  *(float4*)(x) = *(const float4*)sp;
  *(float4*)(x + 4) = *(const float4*)(sp + 4);
  uint hw[4], lw[4];
#pragma unroll
  for (int p = 0; p < 4; ++p) {
    float a = x[2 * p], cc = x[2 * p + 1];
    uint ha = bf16_rne_bits(a), hc = bf16_rne_bits(cc);
    float ra = a - bits_to_f32(ha);
    float rc = cc - bits_to_f32(hc);
    uint la = bf16_rne_bits(ra), lc = bf16_rne_bits(rc);
    hw[p] = ha | (hc << 16);
    lw[p] = la | (lc << 16);
  }
  const size_t dstByte = ((size_t)(cid >> 2) << 6) +
                         (uint)((c ^ ((row >> 1) & 3)) << 4);
  *(uint4*)(dhi + dstByte) = make_uint4(hw[0], hw[1], hw[2], hw[3]);
  *(uint4*)(dlo + dstByte) = make_uint4(lw[0], lw[1], lw[2], lw[3]);
}

// q variant: also emits per-dsi32 partial of q_row . ksum[b]  (16 planes)
__global__ __launch_bounds__(256) void kConvertQdot(const float* __restrict__ src,
                                                    const float* __restrict__ ksum,
                                                    unsigned char* __restrict__ dhi,
                                                    unsigned char* __restrict__ dlo,
                                                    float* __restrict__ qdotp) {
  const int cid = blockIdx.x * 256 + threadIdx.x;
  const int c = cid & 3;
  const int row = (cid >> 2) & 127;
  const int dsi = (cid >> 9) & 15;
  const int rt = (cid >> 13) & 31;
  const int b = cid >> 18;
  const int l = rt * 128 + row;
  const int d = dsi * 32 + c * 8;
  const float* sp = src + ((size_t)(b * L_ + l) * D_ + d);
  float x[8];
  *(float4*)(x) = *(const float4*)sp;
  *(float4*)(x + 4) = *(const float4*)(sp + 4);

  const float* kp = ksum + b * D_ + d;
  float dot = 0.f;
#pragma unroll
  for (int i = 0; i < 8; ++i) dot += x[i] * kp[i];
  dot += __shfl_xor(dot, 1);
  dot += __shfl_xor(dot, 2);

  uint hw[4], lw[4];
#pragma unroll
  for (int p = 0; p < 4; ++p) {
    float a = x[2 * p], cc = x[2 * p + 1];
    uint ha = bf16_rne_bits(a), hc = bf16_rne_bits(cc);
    float ra = a - bits_to_f32(ha);
    float rc = cc - bits_to_f32(hc);
    uint la = bf16_rne_bits(ra), lc = bf16_rne_bits(rc);
    hw[p] = ha | (hc << 16);
    lw[p] = la | (lc << 16);
  }
  const size_t dstByte = ((size_t)(cid >> 2) << 6) +
                         (uint)((c ^ ((row >> 1) & 3)) << 4);
  *(uint4*)(dhi + dstByte) = make_uint4(hw[0], hw[1], hw[2], hw[3]);
  *(uint4*)(dlo + dstByte) = make_uint4(lw[0], lw[1], lw[2], lw[3]);
  if (c == 0)
    qdotp[((size_t)dsi * B_ * L_) + b * L_ + l] = dot;
}

__global__ __launch_bounds__(256) void kQdotReduce(const float* __restrict__ qdotp,
                                                   float* __restrict__ qdot) {
  const int gid = blockIdx.x * 256 + threadIdx.x;
  float s = 0.f;
#pragma unroll
  for (int i = 0; i < 16; ++i) s += qdotp[(size_t)i * B_ * L_ + gid];
  qdot[gid] = s;
}

__device__ __forceinline__ void gload16(const unsigned char* g, unsigned char* l) {
  __builtin_amdgcn_global_load_lds(
      (const __attribute__((address_space(1))) unsigned int*)(g),
      (__attribute__((address_space(3))) unsigned int*)(l), 16, 0, 0);
}

// row max of QK^T: BK=32, double-buffered (2x32KB), prefetch-1-ahead,
// ONE barrier per phase, 2 blocks/CU. 256 phases of 48 MFMA each.
__global__ __launch_bounds__(256, 2) void kRowMaxD(const unsigned char* __restrict__ qhi,
                                                   const unsigned char* __restrict__ qlo,
                                                   const unsigned char* __restrict__ khi,
                                                   const unsigned char* __restrict__ klo,
                                                   float* __restrict__ pmax) {
  __shared__ unsigned char lds[65536];   // buf0 | buf1, each Qhi|Qlo|Khi|Klo @8KB
  __shared__ float red[256];
  unsigned char* buf0 = lds;
  unsigned char* buf1 = lds + 32768;

  const int b = blockIdx.y;
  const int qt = blockIdx.x;
  const int kh = blockIdx.z;
  const int tid = threadIdx.x;
  const int lane = tid & 63;
  const int wave = tid >> 6;
  const int wq = wave >> 1, wk = wave & 1;
  const int g4 = lane >> 4;

  // tiles: 16 planes x 8KB = 128KB per 128-row tile
  const unsigned char* qhB = qhi + (size_t)(b * 32 + qt) * 131072;
  const unsigned char* qlB = qlo + (size_t)(b * 32 + qt) * 131072;
  const unsigned char* khB = khi + (size_t)(b * 32 + kh * 16) * 131072;
  const unsigned char* klB = klo + (size_t)(b * 32 + kh * 16) * 131072;

  const size_t lof = (size_t)tid * 16;

  auto STAGE = [&](int s, unsigned char* buf) {
    const int kt = s >> 4, dsi = s & 15;
    const size_t qof = (size_t)dsi * 8192 + lof;
    const size_t kof = (size_t)kt * 131072 + (size_t)dsi * 8192 + lof;
    gload16(qhB + qof, buf + lof);
    gload16(qhB + qof + 4096, buf + lof + 4096);
    gload16(qlB + qof, buf + 8192 + lof);
    gload16(qlB + qof + 4096, buf + 8192 + lof + 4096);
    gload16(khB + kof, buf + 16384 + lof);
    gload16(khB + kof + 4096, buf + 16384 + lof + 4096);
    gload16(klB + kof, buf + 24576 + lof);
    gload16(klB + kof + 4096, buf + 24576 + lof + 4096);
  };

  float rmax[4][4];
  f32x4 acc[4][4];
#pragma unroll
  for (int i = 0; i < 4; ++i)
#pragma unroll
    for (int j = 0; j < 4; ++j) {
      rmax[i][j] = -3.4e38f;
#pragma unroll
      for (int e = 0; e < 4; ++e) acc[i][j][e] = 0.f;
    }

  // precompute per-lane frag byte offsets (rows fixed per f)
  int qaddr[4], kaddr[4];
#pragma unroll
  for (int f = 0; f < 4; ++f) {
    const int qrow = wq * 64 + f * 16 + (lane & 15);
    const int krow = wk * 64 + f * 16 + (lane & 15);
    qaddr[f] = qrow * 64 + ((g4 ^ ((qrow >> 1) & 3)) << 4);
    kaddr[f] = krow * 64 + ((g4 ^ ((krow >> 1) & 3)) << 4);
  }

  auto PHASE = [&](int s, const unsigned char* bufR, unsigned char* bufW) {
    __syncthreads();                  // drains prefetch of bufR; syncs prev readers of bufW
    if (s < 255) STAGE(s + 1, bufW);  // prefetch next (drained at NEXT barrier)
    bf16x8 aH[4], aL[4], bH[4], bL[4];
#pragma unroll
    for (int f = 0; f < 4; ++f) {
      aH[f] = *(const bf16x8*)(bufR + qaddr[f]);
      aL[f] = *(const bf16x8*)(bufR + 8192 + qaddr[f]);
      bH[f] = *(const bf16x8*)(bufR + 16384 + kaddr[f]);
      bL[f] = *(const bf16x8*)(bufR + 24576 + kaddr[f]);
    }
#pragma unroll
    for (int mf = 0; mf < 4; ++mf)
#pragma unroll
      for (int nf = 0; nf < 4; ++nf) {
        acc[mf][nf] = __builtin_amdgcn_mfma_f32_16x16x32_bf16(aH[mf], bH[nf], acc[mf][nf], 0, 0, 0);
        acc[mf][nf] = __builtin_amdgcn_mfma_f32_16x16x32_bf16(aH[mf], bL[nf], acc[mf][nf], 0, 0, 0);
        acc[mf][nf] = __builtin_amdgcn_mfma_f32_16x16x32_bf16(aL[mf], bH[nf], acc[mf][nf], 0, 0, 0);
      }
    if ((s & 15) == 15) {  // end of key-tile: fold + reset
#pragma unroll
      for (int mf = 0; mf < 4; ++mf)
#pragma unroll
        for (int r = 0; r < 4; ++r) {
          float m = fmaxf(fmaxf(acc[mf][0][r], acc[mf][1][r]),
                          fmaxf(acc[mf][2][r], acc[mf][3][r]));
          rmax[mf][r] = fmaxf(rmax[mf][r], m);
#pragma unroll
          for (int nf = 0; nf < 4; ++nf) acc[mf][nf][r] = 0.f;
        }
    }
  };

  STAGE(0, buf0);
  for (int s = 0; s < 256; s += 2) {
    PHASE(s, buf0, buf1);
    PHASE(s + 1, buf1, buf0);
  }

#pragma unroll
  for (int mf = 0; mf < 4; ++mf)
#pragma unroll
    for (int r = 0; r < 4; ++r) {
      float v = rmax[mf][r];
#pragma unroll
      for (int off = 1; off < 16; off <<= 1) v = fmaxf(v, __shfl_xor(v, off));
      rmax[mf][r] = v;
    }

  if ((lane & 15) == 0) {
#pragma unroll
    for (int mf = 0; mf < 4; ++mf)
#pragma unroll
      for (int r = 0; r < 4; ++r) {
        const int rowl = wq * 64 + mf * 16 + ((lane >> 4) << 2) + r;
        red[wk * 128 + rowl] = rmax[mf][r];
      }
  }
  __syncthreads();
  if (tid < 128) {
    pmax[(size_t)kh * B_ * L_ + (size_t)b * L_ + qt * 128 + tid] =
        fmaxf(red[tid], red[128 + tid]);
  }
}

// ======================= fast path: batched selected attention =======================

// gather 41 selected q rows in the BK=32 swizzled layout:
// [b][dsi32:16][row:64][64B]; rows 41..63 zero.
__global__ __launch_bounds__(64) void kGatherQ(const float* __restrict__ q,
                                               const int* __restrict__ topidx,
                                               unsigned char* __restrict__ qselhi,
                                               unsigned char* __restrict__ qsello) {
  const int j = blockIdx.x;    // 0..63
  const int b = blockIdx.y;
  const int lane = threadIdx.x;
  const int dsi = lane >> 2;   // 0..15
  const int c = lane & 3;
  float x[8] = {0.f, 0.f, 0.f, 0.f, 0.f, 0.f, 0.f, 0.f};
  if (j < U_) {
    const int row = topidx[b * U_ + j];
    const float* sp = q + ((size_t)(b * L_ + row)) * D_ + dsi * 32 + c * 8;
    *(float4*)(x) = *(const float4*)sp;
    *(float4*)(x + 4) = *(const float4*)(sp + 4);
  }
  uint hw[4], lw[4];
#pragma unroll
  for (int p = 0; p < 4; ++p) {
    float a = x[2 * p], cc = x[2 * p + 1];
    uint ha = bf16_rne_bits(a), hc = bf16_rne_bits(cc);
    float ra = a - bits_to_f32(ha);
    float rc = cc - bits_to_f32(hc);
    uint la = bf16_rne_bits(ra), lc = bf16_rne_bits(rc);
    hw[p] = ha | (hc << 16);
    lw[p] = la | (lc << 16);
  }
  const size_t dstByte = (size_t)((b * 16 + dsi) * 64 + j) * 64 +
                         (uint)((c ^ ((j >> 1) & 3)) << 4);
  *(uint4*)(qselhi + dstByte) = make_uint4(hw[0], hw[1], hw[2], hw[3]);
  *(uint4*)(qsello + dstByte) = make_uint4(lw[0], lw[1], lw[2], lw[3]);
}

// selected-scores GEMM (BK=32 layout): P[b][j][key] = q_sel . k
__global__ __launch_bounds__(256) void kSelScoresM(const unsigned char* __restrict__ qselhi,
                                                   const unsigned char* __restrict__ qsello,
                                                   const unsigned char* __restrict__ khi,
                                                   const unsigned char* __restrict__ klo,
                                                   float* __restrict__ P) {
  __shared__ unsigned char lds[24576];   // Qhi 4K | Qlo 4K | Khi 8K | Klo 8K
  const int kc = blockIdx.x;
  const int b = blockIdx.y;
  const int tid = threadIdx.x;
  const int lane = tid & 63;
  const int wave = tid >> 6;
  const int wq = wave >> 1, wk = wave & 1;
  const int g4 = lane >> 4;

  const unsigned char* khB = khi + (size_t)(b * 32 + kc) * 131072;
  const unsigned char* klB = klo + (size_t)(b * 32 + kc) * 131072;
  const unsigned char* qhB = qselhi + (size_t)b * 65536;
  const unsigned char* qlB = qsello + (size_t)b * 65536;

  int qaddr[2], kaddr[4];
#pragma unroll
  for (int f = 0; f < 2; ++f) {
    const int qrow = wq * 32 + f * 16 + (lane & 15);
    qaddr[f] = qrow * 64 + ((g4 ^ ((qrow >> 1) & 3)) << 4);
  }
#pragma unroll
  for (int f = 0; f < 4; ++f) {
    const int krow = wk * 64 + f * 16 + (lane & 15);
    kaddr[f] = krow * 64 + ((g4 ^ ((krow >> 1) & 3)) << 4);
  }

  f32x4 acc[2][4];
#pragma unroll
  for (int i = 0; i < 2; ++i)
#pragma unroll
    for (int j = 0; j < 4; ++j)
#pragma unroll
      for (int e = 0; e < 4; ++e) acc[i][j][e] = 0.f;

  const size_t lof = (size_t)tid * 16;
  for (int dsi = 0; dsi < 16; ++dsi) {
    __syncthreads();
    {
      const size_t qof = (size_t)dsi * 4096 + lof;
      const size_t kof = (size_t)dsi * 8192 + lof;
      gload16(qhB + qof, lds + lof);
      gload16(qlB + qof, lds + 4096 + lof);
      gload16(khB + kof, lds + 8192 + lof);
      gload16(khB + kof + 4096, lds + 8192 + lof + 4096);
      gload16(klB + kof, lds + 16384 + lof);
      gload16(klB + kof + 4096, lds + 16384 + lof + 4096);
    }
    __syncthreads();

    bf16x8 aH[2], aL[2], bH[4], bL[4];
#pragma unroll
    for (int f = 0; f < 2; ++f) {
      aH[f] = *(const bf16x8*)(lds + qaddr[f]);
      aL[f] = *(const bf16x8*)(lds + 4096 + qaddr[f]);
    }
#pragma unroll
    for (int f = 0; f < 4; ++f) {
      bH[f] = *(const bf16x8*)(lds + 8192 + kaddr[f]);
      bL[f] = *(const bf16x8*)(lds + 16384 + kaddr[f]);
    }
#pragma unroll
    for (int mf = 0; mf < 2; ++mf)
#pragma unroll
      for (int nf = 0; nf < 4; ++nf) {
        acc[mf][nf] = __builtin_amdgcn_mfma_f32_16x16x32_bf16(aH[mf], bH[nf], acc[mf][nf], 0, 0, 0);
        acc[mf][nf] = __builtin_amdgcn_mfma_f32_16x16x32_bf16(aH[mf], bL[nf], acc[mf][nf], 0, 0, 0);
        acc[mf][nf] = __builtin_amdgcn_mfma_f32_16x16x32_bf16(aL[mf], bH[nf], acc[mf][nf], 0, 0, 0);
      }
  }

#pragma unroll
  for (int mf = 0; mf < 2; ++mf)
#pragma unroll
    for (int nf = 0; nf < 4; ++nf)
#pragma unroll
      for (int r = 0; r < 4; ++r) {
        const int row = wq * 32 + mf * 16 + ((lane >> 4) << 2) + r;
        const int key = kc * 128 + wk * 64 + nf * 16 + (lane & 15);
        if (row < U_)
          P[((size_t)(b * U_ + row)) * L_ + key] = acc[mf][nf][r];
      }
}

__global__ __launch_bounds__(256) void kSoftmaxP(float* __restrict__ P) {
  __shared__ float red[256];
  const int j = blockIdx.x, b = blockIdx.y;
  float* row = P + ((size_t)(b * U_ + j)) * L_;
  const int tid = threadIdx.x;
  float v[16];
  float mx = -3.4e38f;
#pragma unroll
  for (int i = 0; i < 16; ++i) {
    v[i] = row[tid + i * 256];
    mx = fmaxf(mx, v[i]);
  }
  red[tid] = mx;
  __syncthreads();
  for (int s = 128; s > 0; s >>= 1) {
    if (tid < s) red[tid] = fmaxf(red[tid], red[tid + s]);
    __syncthreads();
  }
  mx = red[0];
  __syncthreads();
  float sum = 0.f;
#pragma unroll
  for (int i = 0; i < 16; ++i) {
    float e = expf((v[i] - mx) * SCALE);
    v[i] = e;
    sum += e;
  }
  red[tid] = sum;
  __syncthreads();
  for (int s = 128; s > 0; s >>= 1) {
    if (tid < s) red[tid] += red[tid + s];
    __syncthreads();
  }
  const float inv = 1.f / red[0];
#pragma unroll
  for (int i = 0; i < 16; ++i) row[tid + i * 256] = v[i] * inv;
}

__global__ __launch_bounds__(256) void kPV(const float* __restrict__ P,
                                           const float* __restrict__ v,
                                           float* __restrict__ partial) {
  __shared__ float plds[41 * 128];
  const int kc = blockIdx.x;
  const int dc = blockIdx.y;
  const int b = blockIdx.z;
  const int tid = threadIdx.x;
  const int trow = tid >> 7, dcol = tid & 127;
  float acc[U_];
#pragma unroll
  for (int j = 0; j < U_; ++j) acc[j] = 0.f;

  for (int sub = 0; sub < 4; ++sub) {
    const int key0 = kc * 512 + sub * 128;
    __syncthreads();
    for (int idx = tid; idx < U_ * 128; idx += 256)
      plds[idx] = P[((size_t)(b * U_ + (idx >> 7))) * L_ + key0 + (idx & 127)];
    __syncthreads();
    const float* vp = v + ((size_t)(b * L_ + key0 + trow * 64)) * D_ + dc * 128 + dcol;
    float vv[64];
#pragma unroll
    for (int kk = 0; kk < 64; ++kk) vv[kk] = vp[(size_t)kk * D_];
#pragma unroll
    for (int j = 0; j < U_; ++j) {
      const float4* pr = (const float4*)&plds[j * 128 + trow * 64];
      float a = acc[j];
#pragma unroll
      for (int q4 = 0; q4 < 16; ++q4) {
        float4 p4 = pr[q4];
        a = fmaf(p4.x, vv[q4 * 4 + 0], a);
        a = fmaf(p4.y, vv[q4 * 4 + 1], a);
        a = fmaf(p4.z, vv[q4 * 4 + 2], a);
        a = fmaf(p4.w, vv[q4 * 4 + 3], a);
      }
      acc[j] = a;
    }
  }
  float* pp = partial + ((size_t)((b * 4 + dc) * 16 + kc * 2 + trow)) * (U_ * 128) + dcol;
#pragma unroll
  for (int j = 0; j < U_; ++j) pp[j * 128] = acc[j];
}

__global__ __launch_bounds__(256) void kPVout(const float* __restrict__ partial,
                                              const int* __restrict__ topidx,
                                              float* __restrict__ out) {
  const int j = blockIdx.x, b = blockIdx.y;
  const int tid = threadIdx.x;
  const int l = topidx[b * U_ + j];
#pragma unroll
  for (int h = 0; h < 2; ++h) {
    const int d = tid + h * 256;
    const int dc = d >> 7, dcol = d & 127;
    float s = 0.f;
#pragma unroll
    for (int part = 0; part < 16; ++part)
      s += partial[((size_t)((b * 4 + dc) * 16 + part)) * (U_ * 128) + j * 128 + dcol];
    out[((size_t)(b * L_ + l)) * D_ + d] = s;
  }
}

// ======================= fallback path (round-2, verified) =======================

__device__ inline void stageHalfRow(const float* __restrict__ src,
                                    char* hiBase, char* loBase,
                                    int row, int shalf) {
  const int sw = (row & 7) << 4;
  char* hp = hiBase + row * 128;
  char* lp = loBase + row * 128;
#pragma unroll
  for (int g = 0; g < 4; ++g) {
    f32x4 x0 = *(const f32x4*)(src + g * 8);
    f32x4 x1 = *(const f32x4*)(src + g * 8 + 4);
    float x[8] = {x0.x, x0.y, x0.z, x0.w, x1.x, x1.y, x1.z, x1.w};
    uint hw[4], lw[4];
#pragma unroll
    for (int p = 0; p < 4; ++p) {
      float a = x[2 * p], c = x[2 * p + 1];
      uint ha = bf16_rne_bits(a), hc = bf16_rne_bits(c);
      float ra = a - bits_to_f32(ha);
      float rc = c - bits_to_f32(hc);
      uint la = bf16_rne_bits(ra), lc = bf16_rne_bits(rc);
      hw[p] = ha | (hc << 16);
      lw[p] = la | (lc << 16);
    }
    const int off = (shalf * 64 + g * 16) ^ sw;
    *(uint4*)(hp + off) = make_uint4(hw[0], hw[1], hw[2], hw[3]);
    *(uint4*)(lp + off) = make_uint4(lw[0], lw[1], lw[2], lw[3]);
  }
}

__global__ __launch_bounds__(256, 2) void kRowMaxM(const float* __restrict__ q,
                                                   const float* __restrict__ k,
                                                   float* __restrict__ pmax) {
  __shared__ char lds[65536];
  __shared__ float red[256];
  char* ldsQhi = lds;
  char* ldsQlo = lds + 16384;
  char* ldsKhi = lds + 32768;
  char* ldsKlo = lds + 49152;

  const int b = blockIdx.y;
  const int qbase = blockIdx.x * 128;
  const int kh = blockIdx.z;
  const int tid = threadIdx.x;
  const int lane = tid & 63;
  const int wave = tid >> 6;
  const int wq = wave >> 1, wk = wave & 1;
  const int srow = tid >> 1;
  const int shalf = tid & 1;

  const float* qrow_base = q + ((size_t)b * L_ + qbase + srow) * D_ + shalf * 32;
  const float* krow_base = k + ((size_t)b * L_ + kh * 2048 + srow) * D_ + shalf * 32;

  float rmax[4][4];
#pragma unroll
  for (int i = 0; i < 4; ++i)
#pragma unroll
    for (int j = 0; j < 4; ++j) rmax[i][j] = -3.4e38f;

  for (int kt = 0; kt < 16; ++kt) {
    f32x4 acc[4][4];
#pragma unroll
    for (int i = 0; i < 4; ++i)
#pragma unroll
      for (int j = 0; j < 4; ++j)
#pragma unroll
        for (int e = 0; e < 4; ++e) acc[i][j][e] = 0.f;

    for (int dsi = 0; dsi < 8; ++dsi) {
      __syncthreads();
      stageHalfRow(qrow_base + dsi * 64, ldsQhi, ldsQlo, srow, shalf);
      stageHalfRow(krow_base + (size_t)kt * 128 * D_ + dsi * 64, ldsKhi, ldsKlo, srow, shalf);
      __syncthreads();

#pragma unroll
      for (int h = 0; h < 2; ++h) {
        const int rbyte = h * 64 + ((lane >> 4) << 4);
        bf16x8 aH[4], aL[4], bH[4], bL[4];
#pragma unroll
        for (int f = 0; f < 4; ++f) {
          const int qrow = wq * 64 + f * 16 + (lane & 15);
          const int krow = wk * 64 + f * 16 + (lane & 15);
          const int qoff = qrow * 128 + (rbyte ^ ((qrow & 7) << 4));
          const int koff = krow * 128 + (rbyte ^ ((krow & 7) << 4));
          aH[f] = *(const bf16x8*)(ldsQhi + qoff);
          aL[f] = *(const bf16x8*)(ldsQlo + qoff);
          bH[f] = *(const bf16x8*)(ldsKhi + koff);
          bL[f] = *(const bf16x8*)(ldsKlo + koff);
        }
#pragma unroll
        for (int mf = 0; mf < 4; ++mf)
#pragma unroll
          for (int nf = 0; nf < 4; ++nf) {
            acc[mf][nf] = __builtin_amdgcn_mfma_f32_16x16x32_bf16(aH[mf], bH[nf], acc[mf][nf], 0, 0, 0);
            acc[mf][nf] = __builtin_amdgcn_mfma_f32_16x16x32_bf16(aH[mf], bL[nf], acc[mf][nf], 0, 0, 0);
            acc[mf][nf] = __builtin_amdgcn_mfma_f32_16x16x32_bf16(aL[mf], bH[nf], acc[mf][nf], 0, 0, 0);
          }
      }
    }
#pragma unroll
    for (int mf = 0; mf < 4; ++mf)
#pragma unroll
      for (int r = 0; r < 4; ++r) {
        float m = fmaxf(fmaxf(acc[mf][0][r], acc[mf][1][r]),
                        fmaxf(acc[mf][2][r], acc[mf][3][r]));
        rmax[mf][r] = fmaxf(rmax[mf][r], m);
      }
  }

#pragma unroll
  for (int mf = 0; mf < 4; ++mf)
#pragma unroll
    for (int r = 0; r < 4; ++r) {
      float v = rmax[mf][r];
#pragma unroll
      for (int off = 1; off < 16; off <<= 1) v = fmaxf(v, __shfl_xor(v, off));
      rmax[mf][r] = v;
    }

  if ((lane & 15) == 0) {
#pragma unroll
    for (int mf = 0; mf < 4; ++mf)
#pragma unroll
      for (int r = 0; r < 4; ++r) {
        const int rowl = wq * 64 + mf * 16 + ((lane >> 4) << 2) + r;
        red[wk * 128 + rowl] = rmax[mf][r];
      }
  }
  __syncthreads();
  if (tid < 128) {
    pmax[(size_t)kh * B_ * L_ + (size_t)b * L_ + qbase + tid] =
        fmaxf(red[tid], red[128 + tid]);
  }
}

__global__ __launch_bounds__(256) void kAttnSel(const float* __restrict__ q,
                                                const float* __restrict__ k,
                                                const float* __restrict__ v,
                                                const int* __restrict__ topidx,
                                                float* __restrict__ out) {
  __shared__ float qs[D_];
  __shared__ float sc[L_];
  __shared__ float wred[4];
  __shared__ float sred[256];
  const int b = blockIdx.y;
  const int l_sel = topidx[b * U_ + blockIdx.x];
  const int tid = threadIdx.x;
  const int wave = tid >> 6, lane = tid & 63;
  const float* qrow = q + ((size_t)b * L_ + l_sel) * D_;
  qs[tid] = qrow[tid];
  qs[tid + 256] = qrow[tid + 256];
  __syncthreads();
  float qr[8];
#pragma unroll
  for (int i = 0; i < 8; ++i) qr[i] = qs[lane * 8 + i];
  float wmax = -3.4e38f;
  for (int l = wave; l < L_; l += 4) {
    const float* kp = k + ((size_t)b * L_ + l) * D_ + lane * 8;
    float4 k0 = *(const float4*)kp;
    float4 k1 = *(const float4*)(kp + 4);
    float p = k0.x * qr[0] + k0.y * qr[1] + k0.z * qr[2] + k0.w * qr[3] +
              k1.x * qr[4] + k1.y * qr[5] + k1.z * qr[6] + k1.w * qr[7];
#pragma unroll
    for (int off = 32; off > 0; off >>= 1) p += __shfl_xor(p, off);
    if (lane == 0) sc[l] = p;
    wmax = fmaxf(wmax, p);
  }
  if (lane == 0) wred[wave] = wmax;
  __syncthreads();
  const float mx = fmaxf(fmaxf(wred[0], wred[1]), fmaxf(wred[2], wred[3]));
  float psum = 0.f;
  for (int i = tid; i < L_; i += 256) {
    float e = expf((sc[i] - mx) * SCALE);
    sc[i] = e;
    psum += e;
  }
  sred[tid] = psum;
  __syncthreads();
  for (int s = 128; s > 0; s >>= 1) {
    if (tid < s) sred[tid] += sred[tid + s];
    __syncthreads();
  }
  const float inv = 1.f / sred[0];
  float a0a = 0.f, a0b = 0.f, a1a = 0.f, a1b = 0.f;
  const float* vb = v + (size_t)b * L_ * D_;
  for (int l = 0; l < L_; l += 2) {
    float p0 = sc[l], p1 = sc[l + 1];
    const float* vp0 = vb + (size_t)l * D_;
    const float* vp1 = vp0 + D_;
    a0a = fmaf(p0, vp0[tid], a0a);
    a1a = fmaf(p0, vp0[tid + 256], a1a);
    a0b = fmaf(p1, vp1[tid], a0b);
    a1b = fmaf(p1, vp1[tid + 256], a1b);
  }
  float* orow = out + ((size_t)b * L_ + l_sel) * D_;
  orow[tid] = (a0a + a0b) * inv;
  orow[tid + 256] = (a1a + a1b) * inv;
}

// ======================= launcher =======================

extern "C" void kernel_launch(void* const* d_in, const int* in_sizes, int n_in,
                              void* d_out, int out_size, void* d_ws, size_t ws_size,
                              hipStream_t stream) {
  const float* q = (const float*)d_in[0];
  const float* k = (const float*)d_in[1];
  const float* v = (const float*)d_in[2];
  float* out = (float*)d_out;
  unsigned char* wsb = (unsigned char*)d_ws;

  const size_t NEED = 71731200;  // fast-path ws bytes

  if (ws_size >= NEED) {
    // ---- fast path ----
    unsigned char* qhiW = wsb;                       // 33554432
    unsigned char* qloW = wsb + 33554432;            // 33554432
    float* P = (float*)wsb;                          // 5373952  (after kRowMaxD)
    float* partial = (float*)(wsb + 5373952);        // 10747904
    unsigned char* qselhi = wsb + 16121856;          // 524288
    unsigned char* qsello = wsb + 16646144;          // 524288
    float* pmax = (float*)(wsb + 67108864);          // 262144
    float* qdot = (float*)(wsb + 67371008);          // 131072
    float* ksum = (float*)(wsb + 67502080);          // 16384
    float* vmean = (float*)(wsb + 67518464);         // 16384
    int* tidx = (int*)(wsb + 67534848);              // 2048
    float* partk = (float*)(wsb + 67536896);         // 2097152
    float* partv = (float*)(wsb + 69634048);         // 2097152 -> 71731200
    // qdotp: 16 planes x B*L floats = 2 MB, aliases partk (dead after kSums2V)
    float* qdotp = partk;

    unsigned char* khiO = (unsigned char*)d_out;
    unsigned char* kloO = khiO + 33554432;

    kSumsV4<<<dim3(NSL, B_), 512, 0, stream>>>(k, v, partk, partv);
    kSums2V<<<B_, 512, 0, stream>>>(partk, partv, ksum, vmean);
    kConvertQdot<<<8192, 256, 0, stream>>>(q, ksum, qhiW, qloW, qdotp);
    kQdotReduce<<<B_ * L_ / 256, 256, 0, stream>>>(qdotp, qdot);
    kConvert<<<8192, 256, 0, stream>>>(k, khiO, kloO);
    kRowMaxD<<<dim3(32, B_, 2), 256, 0, stream>>>(qhiW, qloW, khiO, kloO, pmax);
    kTopK4<<<B_, 64, 0, stream>>>(pmax, qdot, tidx);
    kGatherQ<<<dim3(64, B_), 64, 0, stream>>>(q, tidx, qselhi, qsello);
    kSelScoresM<<<dim3(32, B_), 256, 0, stream>>>(qselhi, qsello, khiO, kloO, P);
    kSoftmaxP<<<dim3(U_, B_), 256, 0, stream>>>(P);
    kFill<<<B_ * L_ * D_ / 1024, 256, 0, stream>>>(vmean, out);
    kPV<<<dim3(8, 4, B_), 256, 0, stream>>>(P, v, partial);
    kPVout<<<dim3(U_, B_), 256, 0, stream>>>(partial, tidx, out);
  } else {
    // ---- fallback: round-2 verified path ----
    float* ws = (float*)d_ws;
    float* Marr = ws;
    float* pmax = ws + 32768;
    float* ksum = ws + 98304;
    float* vmean = ws + 102400;
    int* tidx = (int*)(ws + 106496);
    float* partk = ws + 107008;
    float* partv = ws + 107008 + B_ * NSL * D_;

    kSums1<<<dim3(NSL, B_), 512, 0, stream>>>(k, v, partk, partv);
    kSums2<<<B_, 512, 0, stream>>>(partk, partv, ksum, vmean);
    kRowMaxM<<<dim3(L_ / 128, B_, 2), 256, 0, stream>>>(q, k, pmax);
    kMeanM<<<B_ * L_ / 256, 256, 0, stream>>>(q, ksum, pmax, Marr);
    kTopK3<<<B_, 256, 0, stream>>>(Marr, tidx);
    kFill<<<B_ * L_ * D_ / 1024, 256, 0, stream>>>(vmean, out);
    kAttnSel<<<dim3(U_, B_), 256, 0, stream>>>(q, k, v, tidx, out);
  }
}

// Round 9
// 594.644 us; speedup vs baseline: 1.0977x; 1.0977x over previous
//
#include <hip/hip_runtime.h>
#include <math.h>

#define B_ 8
#define L_ 4096
#define D_ 512
#define U_ 41      // int(5 * ln(4097)) = 41
#define NSL 32

static constexpr float SCALE = 0.044194173824159216f;  // 512^-0.5

typedef __attribute__((ext_vector_type(8))) short bf16x8;
typedef __attribute__((ext_vector_type(4))) float f32x4;
typedef unsigned int uint;

// ======================= bf16 split helpers =======================
__device__ inline uint bf16_rne_bits(float x) {
  uint u = __builtin_bit_cast(uint, x);
  return (u + 0x7FFFu + ((u >> 16) & 1u)) >> 16;
}
__device__ inline float bits_to_f32(uint hi16) {
  return __builtin_bit_cast(float, hi16 << 16);
}

// ======================= fused: convert K + partial sums of k,v =======================
// One pass over k (convert to hi/lo swizzled tiles + column sums) and v (column sums).
// Layout (identical to round-7 kConvert): [b][rt:32][dsi:8][row:128][128B],
// byte-in-row = c16*16 ^ ((row&7)<<4).
// Partials: partk/partv[(b*128 + rt*4 + rg)*D + d], matching kSums2V.
__global__ __launch_bounds__(256) void kSumKV(const float* __restrict__ k,
                                              const float* __restrict__ v,
                                              unsigned char* __restrict__ dhi,
                                              unsigned char* __restrict__ dlo,
                                              float* __restrict__ partk,
                                              float* __restrict__ partv) {
  const int rt = blockIdx.x;           // 0..31
  const int b = blockIdx.y;
  const int tid = threadIdx.x;
  const int rg = tid >> 6;             // 0..3 row group (32 rows each)
  const int c = tid & 63;              // col chunk 0..63 (8 floats)
  const int dsi = c >> 3, c16 = c & 7;
  const int d = c * 8;

  const size_t kbase = ((size_t)(b * L_ + rt * 128 + rg * 32)) * D_ + d;
  const size_t dstBase = (size_t)b * 4194304 + (size_t)rt * 131072 +
                         (size_t)dsi * 16384 + (uint)((c16 << 4) ^ 0);  // row term added below

  float ks[8] = {0.f, 0.f, 0.f, 0.f, 0.f, 0.f, 0.f, 0.f};
  float vs[8] = {0.f, 0.f, 0.f, 0.f, 0.f, 0.f, 0.f, 0.f};

  for (int i = 0; i < 32; ++i) {
    const int row = rg * 32 + i;
    float x[8];
    *(float4*)(x) = *(const float4*)(k + kbase + (size_t)i * D_);
    *(float4*)(x + 4) = *(const float4*)(k + kbase + (size_t)i * D_ + 4);
    uint hw[4], lw[4];
#pragma unroll
    for (int p = 0; p < 4; ++p) {
      float a = x[2 * p], cc = x[2 * p + 1];
      uint ha = bf16_rne_bits(a), hc = bf16_rne_bits(cc);
      float ra = a - bits_to_f32(ha);
      float rc = cc - bits_to_f32(hc);
      uint la = bf16_rne_bits(ra), lc = bf16_rne_bits(rc);
      hw[p] = ha | (hc << 16);
      lw[p] = la | (lc << 16);
    }
    const size_t dstByte = (size_t)b * 4194304 + (size_t)rt * 131072 +
                           (size_t)dsi * 16384 + (size_t)row * 128 +
                           (uint)((c16 << 4) ^ ((row & 7) << 4));
    *(uint4*)(dhi + dstByte) = make_uint4(hw[0], hw[1], hw[2], hw[3]);
    *(uint4*)(dlo + dstByte) = make_uint4(lw[0], lw[1], lw[2], lw[3]);
#pragma unroll
    for (int e = 0; e < 8; ++e) ks[e] += x[e];

    float y[8];
    *(float4*)(y) = *(const float4*)(v + kbase + (size_t)i * D_);
    *(float4*)(y + 4) = *(const float4*)(v + kbase + (size_t)i * D_ + 4);
#pragma unroll
    for (int e = 0; e < 8; ++e) vs[e] += y[e];
  }
  const size_t pb = ((size_t)(b * 128 + rt * 4 + rg)) * D_ + d;
  *(float4*)(partk + pb) = *(float4*)(ks);
  *(float4*)(partk + pb + 4) = *(float4*)(ks + 4);
  *(float4*)(partv + pb) = *(float4*)(vs);
  *(float4*)(partv + pb + 4) = *(float4*)(vs + 4);
}

__global__ __launch_bounds__(512) void kSums2V(const float* __restrict__ partk,
                                               const float* __restrict__ partv,
                                               float* __restrict__ ksum,
                                               float* __restrict__ vmean) {
  const int b = blockIdx.x;
  const int d = threadIdx.x;
  float ks = 0.f, vs = 0.f;
  for (int p = 0; p < 128; ++p) {
    ks += partk[((size_t)(b * 128 + p)) * D_ + d];
    vs += partv[((size_t)(b * 128 + p)) * D_ + d];
  }
  ksum[b * D_ + d] = ks;
  vmean[b * D_ + d] = vs * (1.f / L_);
}

// ======================= fallback-path kernels =======================
__global__ __launch_bounds__(512) void kSums1(const float* __restrict__ k,
                                              const float* __restrict__ v,
                                              float* __restrict__ partk,
                                              float* __restrict__ partv) {
  const int s = blockIdx.x;
  const int b = blockIdx.y;
  const int d = threadIdx.x;
  const int rows = L_ / NSL;
  const size_t base = ((size_t)b * L_ + (size_t)s * rows) * D_ + d;
  float ks = 0.f, vs = 0.f;
  for (int l = 0; l < rows; ++l) {
    ks += k[base + (size_t)l * D_];
    vs += v[base + (size_t)l * D_];
  }
  partk[(b * NSL + s) * D_ + d] = ks;
  partv[(b * NSL + s) * D_ + d] = vs;
}

__global__ __launch_bounds__(512) void kSums2(const float* __restrict__ partk,
                                              const float* __restrict__ partv,
                                              float* __restrict__ ksum,
                                              float* __restrict__ vmean) {
  const int b = blockIdx.x;
  const int d = threadIdx.x;
  float ks = 0.f, vs = 0.f;
  for (int s = 0; s < NSL; ++s) {
    ks += partk[(b * NSL + s) * D_ + d];
    vs += partv[(b * NSL + s) * D_ + d];
  }
  ksum[b * D_ + d] = ks;
  vmean[b * D_ + d] = vs * (1.f / L_);
}

__global__ __launch_bounds__(256) void kMeanM(const float* __restrict__ q,
                                              const float* __restrict__ ksum,
                                              const float* __restrict__ pmax,
                                              float* __restrict__ M) {
  __shared__ float ks[D_];
  const int gid = blockIdx.x * 256 + threadIdx.x;
  const int b = gid >> 12;
  for (int i = threadIdx.x; i < D_; i += 256) ks[i] = ksum[b * D_ + i];
  __syncthreads();
  const float* qp = q + (size_t)gid * D_;
  float acc = 0.f;
  for (int i = 0; i < D_; i += 4) {
    float4 t = *(const float4*)(qp + i);
    acc += t.x * ks[i] + t.y * ks[i + 1] + t.z * ks[i + 2] + t.w * ks[i + 3];
  }
  const float rowmax = fmaxf(pmax[gid], pmax[B_ * L_ + gid]);
  M[gid] = SCALE * (rowmax - acc * (1.f / L_));
}

__global__ __launch_bounds__(256) void kTopK3(const float* __restrict__ M,
                                              int* __restrict__ topidx) {
  __shared__ float wv[2][4];
  __shared__ int wi[2][4];
  const int b = blockIdx.x;
  const int tid = threadIdx.x;
  const int wave = tid >> 6, lane = tid & 63;
  float v[16];
#pragma unroll
  for (int j = 0; j < 16; ++j) v[j] = M[b * L_ + tid + j * 256];
  float bv = v[0];
  int bj = 0;
#pragma unroll
  for (int j = 1; j < 16; ++j)
    if (v[j] > bv) { bv = v[j]; bj = j; }
  int bi = tid + bj * 256;

  for (int it = 0; it < U_; ++it) {
    float rv = bv;
    int ri = bi;
#pragma unroll
    for (int off = 1; off < 64; off <<= 1) {
      float ov = __shfl_xor(rv, off);
      int oi = __shfl_xor(ri, off);
      if (ov > rv || (ov == rv && oi < ri)) { rv = ov; ri = oi; }
    }
    const int par = it & 1;
    if (lane == 0) { wv[par][wave] = rv; wi[par][wave] = ri; }
    __syncthreads();
    float gv = wv[par][0];
    int gi = wi[par][0];
#pragma unroll
    for (int w = 1; w < 4; ++w) {
      float ov = wv[par][w];
      int oi = wi[par][w];
      if (ov > gv || (ov == gv && oi < gi)) { gv = ov; gi = oi; }
    }
    if (tid == 0) topidx[b * U_ + it] = gi;
    if (gi == bi) {
      const int jb = gi >> 8;
#pragma unroll
      for (int j = 0; j < 16; ++j)
        if (j == jb) v[j] = -3.4e38f;
      bv = v[0];
      bj = 0;
#pragma unroll
      for (int j = 1; j < 16; ++j)
        if (v[j] > bv) { bv = v[j]; bj = j; }
      bi = tid + bj * 256;
    }
  }
}

// fast-path top-41: single wave per batch, zero barriers, M on the fly
__global__ __launch_bounds__(64) void kTopK4(const float* __restrict__ pmax,
                                             const float* __restrict__ qdot,
                                             int* __restrict__ topidx) {
  const int b = blockIdx.x;
  const int lane = threadIdx.x;
  float v[64];
#pragma unroll
  for (int j = 0; j < 64; ++j) {
    const int gid = b * L_ + lane + j * 64;
    v[j] = SCALE * (fmaxf(pmax[gid], pmax[B_ * L_ + gid]) - qdot[gid] * (1.f / L_));
  }
  float bv = v[0];
  int bj = 0;
#pragma unroll
  for (int j = 1; j < 64; ++j)
    if (v[j] > bv) { bv = v[j]; bj = j; }
  int bi = lane + bj * 64;

  for (int it = 0; it < U_; ++it) {
    float rv = bv;
    int ri = bi;
#pragma unroll
    for (int off = 1; off < 64; off <<= 1) {
      float ov = __shfl_xor(rv, off);
      int oi = __shfl_xor(ri, off);
      if (ov > rv || (ov == rv && oi < ri)) { rv = ov; ri = oi; }
    }
    if (lane == 0) topidx[b * U_ + it] = ri;
    if (ri == bi) {
#pragma unroll
      for (int j = 0; j < 64; ++j)
        if (j == bj) v[j] = -3.4e38f;
      bv = v[0];
      bj = 0;
#pragma unroll
      for (int j = 1; j < 64; ++j)
        if (v[j] > bv) { bv = v[j]; bj = j; }
      bi = lane + bj * 64;
    }
  }
}

__global__ __launch_bounds__(256) void kFill(const float* __restrict__ vmean,
                                             float* __restrict__ out) {
  const int g = blockIdx.x * 256 + threadIdx.x;
  const int d4 = g & 127;
  const int bl = g >> 7;
  const int b = bl >> 12;
  ((float4*)out)[g] = ((const float4*)vmean)[b * 128 + d4];
}

// ======================= q convert + qdot partials (round-7 verified) =======================
__global__ __launch_bounds__(256) void kConvertQdot(const float* __restrict__ src,
                                                    const float* __restrict__ ksum,
                                                    unsigned char* __restrict__ dhi,
                                                    unsigned char* __restrict__ dlo,
                                                    float* __restrict__ qdotp) {
  const int cid = blockIdx.x * 256 + threadIdx.x;
  const int c16 = cid & 7;
  const int row = (cid >> 3) & 127;
  const int dsi = (cid >> 10) & 7;
  const int rt = (cid >> 13) & 31;
  const int b = cid >> 18;
  const int l = rt * 128 + row;
  const int d = dsi * 64 + c16 * 8;
  const float* sp = src + ((size_t)(b * L_ + l) * D_ + d);
  float x[8];
  *(float4*)(x) = *(const float4*)sp;
  *(float4*)(x + 4) = *(const float4*)(sp + 4);

  const float* kp = ksum + b * D_ + d;
  float dot = 0.f;
#pragma unroll
  for (int i = 0; i < 8; ++i) dot += x[i] * kp[i];
#pragma unroll
  for (int off = 1; off < 8; off <<= 1) dot += __shfl_xor(dot, off);

  uint hw[4], lw[4];
#pragma unroll
  for (int p = 0; p < 4; ++p) {
    float a = x[2 * p], c = x[2 * p + 1];
    uint ha = bf16_rne_bits(a), hc = bf16_rne_bits(c);
    float ra = a - bits_to_f32(ha);
    float rc = c - bits_to_f32(hc);
    uint la = bf16_rne_bits(ra), lc = bf16_rne_bits(rc);
    hw[p] = ha | (hc << 16);
    lw[p] = la | (lc << 16);
  }
  const size_t dstByte = ((size_t)(cid >> 3) << 7) +
                         (uint)((c16 << 4) ^ ((row & 7) << 4));
  *(uint4*)(dhi + dstByte) = make_uint4(hw[0], hw[1], hw[2], hw[3]);
  *(uint4*)(dlo + dstByte) = make_uint4(lw[0], lw[1], lw[2], lw[3]);
  if (c16 == 0)
    qdotp[((size_t)dsi * B_ * L_) + b * L_ + l] = dot;
}

__global__ __launch_bounds__(256) void kQdotReduce(const float* __restrict__ qdotp,
                                                   float* __restrict__ qdot) {
  const int gid = blockIdx.x * 256 + threadIdx.x;
  float s = 0.f;
#pragma unroll
  for (int i = 0; i < 8; ++i) s += qdotp[(size_t)i * B_ * L_ + gid];
  qdot[gid] = s;
}

__device__ __forceinline__ void gload16(const unsigned char* g, unsigned char* l) {
  __builtin_amdgcn_global_load_lds(
      (const __attribute__((address_space(1))) unsigned int*)(g),
      (__attribute__((address_space(3))) unsigned int*)(l), 16, 0, 0);
}

// row max of QK^T via pre-converted bf16 split, global_load_lds staging.
// Round-7 measured best: 2 blocks/CU, BK=64, 2-barrier phase, linear grid.
__global__ __launch_bounds__(256, 2) void kRowMaxB(const unsigned char* __restrict__ qhi,
                                                   const unsigned char* __restrict__ qlo,
                                                   const unsigned char* __restrict__ khi,
                                                   const unsigned char* __restrict__ klo,
                                                   float* __restrict__ pmax) {
  __shared__ unsigned char lds[65536];
  __shared__ float red[256];
  unsigned char* ldsQhi = lds;
  unsigned char* ldsQlo = lds + 16384;
  unsigned char* ldsKhi = lds + 32768;
  unsigned char* ldsKlo = lds + 49152;

  const int b = blockIdx.y;
  const int qt = blockIdx.x;
  const int kh = blockIdx.z;
  const int tid = threadIdx.x;
  const int lane = tid & 63;
  const int wave = tid >> 6;
  const int wq = wave >> 1, wk = wave & 1;

  const size_t qtb = ((size_t)((b * 32 + qt) * 8)) * 16384;
  const unsigned char* qhB = qhi + qtb;
  const unsigned char* qlB = qlo + qtb;

  float rmax[4][4];
#pragma unroll
  for (int i = 0; i < 4; ++i)
#pragma unroll
    for (int j = 0; j < 4; ++j) rmax[i][j] = -3.4e38f;

  for (int kt = 0; kt < 16; ++kt) {
    const size_t ktb = ((size_t)((b * 32 + (kh * 16 + kt)) * 8)) * 16384;
    const unsigned char* khB = khi + ktb;
    const unsigned char* klB = klo + ktb;

    f32x4 acc[4][4];
#pragma unroll
    for (int i = 0; i < 4; ++i)
#pragma unroll
      for (int j = 0; j < 4; ++j)
#pragma unroll
        for (int e = 0; e < 4; ++e) acc[i][j][e] = 0.f;

    for (int dsi = 0; dsi < 8; ++dsi) {
      __syncthreads();   // previous step's frag reads complete
      {
        const size_t dof = (size_t)dsi * 16384 + (size_t)tid * 16;
        const size_t lof = (size_t)tid * 16;
#pragma unroll
        for (int i = 0; i < 4; ++i) {
          gload16(qhB + dof + i * 4096, ldsQhi + lof + i * 4096);
          gload16(qlB + dof + i * 4096, ldsQlo + lof + i * 4096);
          gload16(khB + dof + i * 4096, ldsKhi + lof + i * 4096);
          gload16(klB + dof + i * 4096, ldsKlo + lof + i * 4096);
        }
      }
      __syncthreads();   // tiles visible (syncthreads drains vmcnt)

#pragma unroll
      for (int h = 0; h < 2; ++h) {
        const int rbyte = h * 64 + ((lane >> 4) << 4);
        bf16x8 aH[4], aL[4], bH[4], bL[4];
#pragma unroll
        for (int f = 0; f < 4; ++f) {
          const int qrow = wq * 64 + f * 16 + (lane & 15);
          const int krow = wk * 64 + f * 16 + (lane & 15);
          const int qoff = qrow * 128 + (rbyte ^ ((qrow & 7) << 4));
          const int koff = krow * 128 + (rbyte ^ ((krow & 7) << 4));
          aH[f] = *(const bf16x8*)(ldsQhi + qoff);
          aL[f] = *(const bf16x8*)(ldsQlo + qoff);
          bH[f] = *(const bf16x8*)(ldsKhi + koff);
          bL[f] = *(const bf16x8*)(ldsKlo + koff);
        }
#pragma unroll
        for (int mf = 0; mf < 4; ++mf)
#pragma unroll
          for (int nf = 0; nf < 4; ++nf) {
            acc[mf][nf] = __builtin_amdgcn_mfma_f32_16x16x32_bf16(aH[mf], bH[nf], acc[mf][nf], 0, 0, 0);
            acc[mf][nf] = __builtin_amdgcn_mfma_f32_16x16x32_bf16(aH[mf], bL[nf], acc[mf][nf], 0, 0, 0);
            acc[mf][nf] = __builtin_amdgcn_mfma_f32_16x16x32_bf16(aL[mf], bH[nf], acc[mf][nf], 0, 0, 0);
          }
      }
    }
#pragma unroll
    for (int mf = 0; mf < 4; ++mf)
#pragma unroll
      for (int r = 0; r < 4; ++r) {
        float m = fmaxf(fmaxf(acc[mf][0][r], acc[mf][1][r]),
                        fmaxf(acc[mf][2][r], acc[mf][3][r]));
        rmax[mf][r] = fmaxf(rmax[mf][r], m);
      }
  }

#pragma unroll
  for (int mf = 0; mf < 4; ++mf)
#pragma unroll
    for (int r = 0; r < 4; ++r) {
      float v = rmax[mf][r];
#pragma unroll
      for (int off = 1; off < 16; off <<= 1) v = fmaxf(v, __shfl_xor(v, off));
      rmax[mf][r] = v;
    }

  if ((lane & 15) == 0) {
#pragma unroll
    for (int mf = 0; mf < 4; ++mf)
#pragma unroll
      for (int r = 0; r < 4; ++r) {
        const int rowl = wq * 64 + mf * 16 + ((lane >> 4) << 2) + r;
        red[wk * 128 + rowl] = rmax[mf][r];
      }
  }
  __syncthreads();
  if (tid < 128) {
    pmax[(size_t)kh * B_ * L_ + (size_t)b * L_ + qt * 128 + tid] =
        fmaxf(red[tid], red[128 + tid]);
  }
}

// ======================= batched selected attention (round-7 verified) =======================

__global__ __launch_bounds__(64) void kGatherQ(const float* __restrict__ q,
                                               const int* __restrict__ topidx,
                                               unsigned char* __restrict__ qselhi,
                                               unsigned char* __restrict__ qsello) {
  const int j = blockIdx.x;    // 0..63
  const int b = blockIdx.y;
  const int lane = threadIdx.x;
  const int dsi = lane >> 3;
  const int c16 = lane & 7;
  float x[8] = {0.f, 0.f, 0.f, 0.f, 0.f, 0.f, 0.f, 0.f};
  if (j < U_) {
    const int row = topidx[b * U_ + j];
    const float* sp = q + ((size_t)(b * L_ + row)) * D_ + dsi * 64 + c16 * 8;
    *(float4*)(x) = *(const float4*)sp;
    *(float4*)(x + 4) = *(const float4*)(sp + 4);
  }
  uint hw[4], lw[4];
#pragma unroll
  for (int p = 0; p < 4; ++p) {
    float a = x[2 * p], c = x[2 * p + 1];
    uint ha = bf16_rne_bits(a), hc = bf16_rne_bits(c);
    float ra = a - bits_to_f32(ha);
    float rc = c - bits_to_f32(hc);
    uint la = bf16_rne_bits(ra), lc = bf16_rne_bits(rc);
    hw[p] = ha | (hc << 16);
    lw[p] = la | (lc << 16);
  }
  const size_t dstByte = ((size_t)((b * 8 + dsi) * 64 + j)) * 128 +
                         (uint)((c16 << 4) ^ ((j & 7) << 4));
  *(uint4*)(qselhi + dstByte) = make_uint4(hw[0], hw[1], hw[2], hw[3]);
  *(uint4*)(qsello + dstByte) = make_uint4(lw[0], lw[1], lw[2], lw[3]);
}

__global__ __launch_bounds__(256) void kSelScoresM(const unsigned char* __restrict__ qselhi,
                                                   const unsigned char* __restrict__ qsello,
                                                   const unsigned char* __restrict__ khi,
                                                   const unsigned char* __restrict__ klo,
                                                   float* __restrict__ P) {
  __shared__ unsigned char lds[49152];
  unsigned char* ldsQhi = lds;
  unsigned char* ldsQlo = lds + 8192;
  unsigned char* ldsKhi = lds + 16384;
  unsigned char* ldsKlo = lds + 32768;

  const int kc = blockIdx.x;
  const int b = blockIdx.y;
  const int tid = threadIdx.x;
  const int lane = tid & 63;
  const int wave = tid >> 6;
  const int wq = wave >> 1, wk = wave & 1;

  const size_t ktb = ((size_t)((b * 32 + kc) * 8)) * 16384;
  const unsigned char* khB = khi + ktb;
  const unsigned char* klB = klo + ktb;
  const size_t qb = ((size_t)b * 8) * 8192;
  const unsigned char* qhB = qselhi + qb;
  const unsigned char* qlB = qsello + qb;

  f32x4 acc[2][4];
#pragma unroll
  for (int i = 0; i < 2; ++i)
#pragma unroll
    for (int j = 0; j < 4; ++j)
#pragma unroll
      for (int e = 0; e < 4; ++e) acc[i][j][e] = 0.f;

  for (int dsi = 0; dsi < 8; ++dsi) {
    __syncthreads();
    {
      const size_t qof = (size_t)dsi * 8192 + (size_t)tid * 16;
      const size_t kof = (size_t)dsi * 16384 + (size_t)tid * 16;
      const size_t lof = (size_t)tid * 16;
#pragma unroll
      for (int i = 0; i < 2; ++i) {
        gload16(qhB + qof + i * 4096, ldsQhi + lof + i * 4096);
        gload16(qlB + qof + i * 4096, ldsQlo + lof + i * 4096);
      }
#pragma unroll
      for (int i = 0; i < 4; ++i) {
        gload16(khB + kof + i * 4096, ldsKhi + lof + i * 4096);
        gload16(klB + kof + i * 4096, ldsKlo + lof + i * 4096);
      }
    }
    __syncthreads();

#pragma unroll
    for (int h = 0; h < 2; ++h) {
      const int rbyte = h * 64 + ((lane >> 4) << 4);
      bf16x8 aH[2], aL[2], bH[4], bL[4];
#pragma unroll
      for (int f = 0; f < 2; ++f) {
        const int qrow = wq * 32 + f * 16 + (lane & 15);
        const int qoff = qrow * 128 + (rbyte ^ ((qrow & 7) << 4));
        aH[f] = *(const bf16x8*)(ldsQhi + qoff);
        aL[f] = *(const bf16x8*)(ldsQlo + qoff);
      }
#pragma unroll
      for (int f = 0; f < 4; ++f) {
        const int krow = wk * 64 + f * 16 + (lane & 15);
        const int koff = krow * 128 + (rbyte ^ ((krow & 7) << 4));
        bH[f] = *(const bf16x8*)(ldsKhi + koff);
        bL[f] = *(const bf16x8*)(ldsKlo + koff);
      }
#pragma unroll
      for (int mf = 0; mf < 2; ++mf)
#pragma unroll
        for (int nf = 0; nf < 4; ++nf) {
          acc[mf][nf] = __builtin_amdgcn_mfma_f32_16x16x32_bf16(aH[mf], bH[nf], acc[mf][nf], 0, 0, 0);
          acc[mf][nf] = __builtin_amdgcn_mfma_f32_16x16x32_bf16(aH[mf], bL[nf], acc[mf][nf], 0, 0, 0);
          acc[mf][nf] = __builtin_amdgcn_mfma_f32_16x16x32_bf16(aL[mf], bH[nf], acc[mf][nf], 0, 0, 0);
        }
    }
  }

#pragma unroll
  for (int mf = 0; mf < 2; ++mf)
#pragma unroll
    for (int nf = 0; nf < 4; ++nf)
#pragma unroll
      for (int r = 0; r < 4; ++r) {
        const int row = wq * 32 + mf * 16 + ((lane >> 4) << 2) + r;
        const int key = kc * 128 + wk * 64 + nf * 16 + (lane & 15);
        if (row < U_)
          P[((size_t)(b * U_ + row)) * L_ + key] = acc[mf][nf][r];
      }
}

__global__ __launch_bounds__(256) void kSoftmaxP(float* __restrict__ P) {
  __shared__ float red[256];
  const int j = blockIdx.x, b = blockIdx.y;
  float* row = P + ((size_t)(b * U_ + j)) * L_;
  const int tid = threadIdx.x;
  float v[16];
  float mx = -3.4e38f;
#pragma unroll
  for (int i = 0; i < 16; ++i) {
    v[i] = row[tid + i * 256];
    mx = fmaxf(mx, v[i]);
  }
  red[tid] = mx;
  __syncthreads();
  for (int s = 128; s > 0; s >>= 1) {
    if (tid < s) red[tid] = fmaxf(red[tid], red[tid + s]);
    __syncthreads();
  }
  mx = red[0];
  __syncthreads();
  float sum = 0.f;
#pragma unroll
  for (int i = 0; i < 16; ++i) {
    float e = expf((v[i] - mx) * SCALE);
    v[i] = e;
    sum += e;
  }
  red[tid] = sum;
  __syncthreads();
  for (int s = 128; s > 0; s >>= 1) {
    if (tid < s) red[tid] += red[tid + s];
    __syncthreads();
  }
  const float inv = 1.f / red[0];
#pragma unroll
  for (int i = 0; i < 16; ++i) row[tid + i * 256] = v[i] * inv;
}

__global__ __launch_bounds__(256) void kPV(const float* __restrict__ P,
                                           const float* __restrict__ v,
                                           float* __restrict__ partial) {
  __shared__ float plds[41 * 128];
  const int kc = blockIdx.x;
  const int dc = blockIdx.y;
  const int b = blockIdx.z;
  const int tid = threadIdx.x;
  const int trow = tid >> 7, dcol = tid & 127;
  float acc[U_];
#pragma unroll
  for (int j = 0; j < U_; ++j) acc[j] = 0.f;

  for (int sub = 0; sub < 4; ++sub) {
    const int key0 = kc * 512 + sub * 128;
    __syncthreads();
    for (int idx = tid; idx < U_ * 128; idx += 256)
      plds[idx] = P[((size_t)(b * U_ + (idx >> 7))) * L_ + key0 + (idx & 127)];
    __syncthreads();
    const float* vp = v + ((size_t)(b * L_ + key0 + trow * 64)) * D_ + dc * 128 + dcol;
    float vv[64];
#pragma unroll
    for (int kk = 0; kk < 64; ++kk) vv[kk] = vp[(size_t)kk * D_];
#pragma unroll
    for (int j = 0; j < U_; ++j) {
      const float4* pr = (const float4*)&plds[j * 128 + trow * 64];
      float a = acc[j];
#pragma unroll
      for (int q4 = 0; q4 < 16; ++q4) {
        float4 p4 = pr[q4];
        a = fmaf(p4.x, vv[q4 * 4 + 0], a);
        a = fmaf(p4.y, vv[q4 * 4 + 1], a);
        a = fmaf(p4.z, vv[q4 * 4 + 2], a);
        a = fmaf(p4.w, vv[q4 * 4 + 3], a);
      }
      acc[j] = a;
    }
  }
  float* pp = partial + ((size_t)((b * 4 + dc) * 16 + kc * 2 + trow)) * (U_ * 128) + dcol;
#pragma unroll
  for (int j = 0; j < U_; ++j) pp[j * 128] = acc[j];
}

__global__ __launch_bounds__(256) void kPVout(const float* __restrict__ partial,
                                              const int* __restrict__ topidx,
                                              float* __restrict__ out) {
  const int j = blockIdx.x, b = blockIdx.y;
  const int tid = threadIdx.x;
  const int l = topidx[b * U_ + j];
#pragma unroll
  for (int h = 0; h < 2; ++h) {
    const int d = tid + h * 256;
    const int dc = d >> 7, dcol = d & 127;
    float s = 0.f;
#pragma unroll
    for (int part = 0; part < 16; ++part)
      s += partial[((size_t)((b * 4 + dc) * 16 + part)) * (U_ * 128) + j * 128 + dcol];
    out[((size_t)(b * L_ + l)) * D_ + d] = s;
  }
}

// ======================= fallback path (round-2, verified) =======================

__device__ inline void stageHalfRow(const float* __restrict__ src,
                                    char* hiBase, char* loBase,
                                    int row, int shalf) {
  const int sw = (row & 7) << 4;
  char* hp = hiBase + row * 128;
  char* lp = loBase + row * 128;
#pragma unroll
  for (int g = 0; g < 4; ++g) {
    f32x4 x0 = *(const f32x4*)(src + g * 8);
    f32x4 x1 = *(const f32x4*)(src + g * 8 + 4);
    float x[8] = {x0.x, x0.y, x0.z, x0.w, x1.x, x1.y, x1.z, x1.w};
    uint hw[4], lw[4];
#pragma unroll
    for (int p = 0; p < 4; ++p) {
      float a = x[2 * p], c = x[2 * p + 1];
      uint ha = bf16_rne_bits(a), hc = bf16_rne_bits(c);
      float ra = a - bits_to_f32(ha);
      float rc = c - bits_to_f32(hc);
      uint la = bf16_rne_bits(ra), lc = bf16_rne_bits(rc);
      hw[p] = ha | (hc << 16);
      lw[p] = la | (lc << 16);
    }
    const int off = (shalf * 64 + g * 16) ^ sw;
    *(uint4*)(hp + off) = make_uint4(hw[0], hw[1], hw[2], hw[3]);
    *(uint4*)(lp + off) = make_uint4(lw[0], lw[1], lw[2], lw[3]);
  }
}

__global__ __launch_bounds__(256, 2) void kRowMaxM(const float* __restrict__ q,
                                                   const float* __restrict__ k,
                                                   float* __restrict__ pmax) {
  __shared__ char lds[65536];
  __shared__ float red[256];
  char* ldsQhi = lds;
  char* ldsQlo = lds + 16384;
  char* ldsKhi = lds + 32768;
  char* ldsKlo = lds + 49152;

  const int b = blockIdx.y;
  const int qbase = blockIdx.x * 128;
  const int kh = blockIdx.z;
  const int tid = threadIdx.x;
  const int lane = tid & 63;
  const int wave = tid >> 6;
  const int wq = wave >> 1, wk = wave & 1;
  const int srow = tid >> 1;
  const int shalf = tid & 1;

  const float* qrow_base = q + ((size_t)b * L_ + qbase + srow) * D_ + shalf * 32;
  const float* krow_base = k + ((size_t)b * L_ + kh * 2048 + srow) * D_ + shalf * 32;

  float rmax[4][4];
#pragma unroll
  for (int i = 0; i < 4; ++i)
#pragma unroll
    for (int j = 0; j < 4; ++j) rmax[i][j] = -3.4e38f;

  for (int kt = 0; kt < 16; ++kt) {
    f32x4 acc[4][4];
#pragma unroll
    for (int i = 0; i < 4; ++i)
#pragma unroll
      for (int j = 0; j < 4; ++j)
#pragma unroll
        for (int e = 0; e < 4; ++e) acc[i][j][e] = 0.f;

    for (int dsi = 0; dsi < 8; ++dsi) {
      __syncthreads();
      stageHalfRow(qrow_base + dsi * 64, ldsQhi, ldsQlo, srow, shalf);
      stageHalfRow(krow_base + (size_t)kt * 128 * D_ + dsi * 64, ldsKhi, ldsKlo, srow, shalf);
      __syncthreads();

#pragma unroll
      for (int h = 0; h < 2; ++h) {
        const int rbyte = h * 64 + ((lane >> 4) << 4);
        bf16x8 aH[4], aL[4], bH[4], bL[4];
#pragma unroll
        for (int f = 0; f < 4; ++f) {
          const int qrow = wq * 64 + f * 16 + (lane & 15);
          const int krow = wk * 64 + f * 16 + (lane & 15);
          const int qoff = qrow * 128 + (rbyte ^ ((qrow & 7) << 4));
          const int koff = krow * 128 + (rbyte ^ ((krow & 7) << 4));
          aH[f] = *(const bf16x8*)(ldsQhi + qoff);
          aL[f] = *(const bf16x8*)(ldsQlo + qoff);
          bH[f] = *(const bf16x8*)(ldsKhi + koff);
          bL[f] = *(const bf16x8*)(ldsKlo + koff);
        }
#pragma unroll
        for (int mf = 0; mf < 4; ++mf)
#pragma unroll
          for (int nf = 0; nf < 4; ++nf) {
            acc[mf][nf] = __builtin_amdgcn_mfma_f32_16x16x32_bf16(aH[mf], bH[nf], acc[mf][nf], 0, 0, 0);
            acc[mf][nf] = __builtin_amdgcn_mfma_f32_16x16x32_bf16(aH[mf], bL[nf], acc[mf][nf], 0, 0, 0);
            acc[mf][nf] = __builtin_amdgcn_mfma_f32_16x16x32_bf16(aL[mf], bH[nf], acc[mf][nf], 0, 0, 0);
          }
      }
    }
#pragma unroll
    for (int mf = 0; mf < 4; ++mf)
#pragma unroll
      for (int r = 0; r < 4; ++r) {
        float m = fmaxf(fmaxf(acc[mf][0][r], acc[mf][1][r]),
                        fmaxf(acc[mf][2][r], acc[mf][3][r]));
        rmax[mf][r] = fmaxf(rmax[mf][r], m);
      }
  }

#pragma unroll
  for (int mf = 0; mf < 4; ++mf)
#pragma unroll
    for (int r = 0; r < 4; ++r) {
      float v = rmax[mf][r];
#pragma unroll
      for (int off = 1; off < 16; off <<= 1) v = fmaxf(v, __shfl_xor(v, off));
      rmax[mf][r] = v;
    }

  if ((lane & 15) == 0) {
#pragma unroll
    for (int mf = 0; mf < 4; ++mf)
#pragma unroll
      for (int r = 0; r < 4; ++r) {
        const int rowl = wq * 64 + mf * 16 + ((lane >> 4) << 2) + r;
        red[wk * 128 + rowl] = rmax[mf][r];
      }
  }
  __syncthreads();
  if (tid < 128) {
    pmax[(size_t)kh * B_ * L_ + (size_t)b * L_ + qbase + tid] =
        fmaxf(red[tid], red[128 + tid]);
  }
}

__global__ __launch_bounds__(256) void kAttnSel(const float* __restrict__ q,
                                                const float* __restrict__ k,
                                                const float* __restrict__ v,
                                                const int* __restrict__ topidx,
                                                float* __restrict__ out) {
  __shared__ float qs[D_];
  __shared__ float sc[L_];
  __shared__ float wred[4];
  __shared__ float sred[256];
  const int b = blockIdx.y;
  const int l_sel = topidx[b * U_ + blockIdx.x];
  const int tid = threadIdx.x;
  const int wave = tid >> 6, lane = tid & 63;
  const float* qrow = q + ((size_t)b * L_ + l_sel) * D_;
  qs[tid] = qrow[tid];
  qs[tid + 256] = qrow[tid + 256];
  __syncthreads();
  float qr[8];
#pragma unroll
  for (int i = 0; i < 8; ++i) qr[i] = qs[lane * 8 + i];
  float wmax = -3.4e38f;
  for (int l = wave; l < L_; l += 4) {
    const float* kp = k + ((size_t)b * L_ + l) * D_ + lane * 8;
    float4 k0 = *(const float4*)kp;
    float4 k1 = *(const float4*)(kp + 4);
    float p = k0.x * qr[0] + k0.y * qr[1] + k0.z * qr[2] + k0.w * qr[3] +
              k1.x * qr[4] + k1.y * qr[5] + k1.z * qr[6] + k1.w * qr[7];
#pragma unroll
    for (int off = 32; off > 0; off >>= 1) p += __shfl_xor(p, off);
    if (lane == 0) sc[l] = p;
    wmax = fmaxf(wmax, p);
  }
  if (lane == 0) wred[wave] = wmax;
  __syncthreads();
  const float mx = fmaxf(fmaxf(wred[0], wred[1]), fmaxf(wred[2], wred[3]));
  float psum = 0.f;
  for (int i = tid; i < L_; i += 256) {
    float e = expf((sc[i] - mx) * SCALE);
    sc[i] = e;
    psum += e;
  }
  sred[tid] = psum;
  __syncthreads();
  for (int s = 128; s > 0; s >>= 1) {
    if (tid < s) sred[tid] += sred[tid + s];
    __syncthreads();
  }
  const float inv = 1.f / sred[0];
  float a0a = 0.f, a0b = 0.f, a1a = 0.f, a1b = 0.f;
  const float* vb = v + (size_t)b * L_ * D_;
  for (int l = 0; l < L_; l += 2) {
    float p0 = sc[l], p1 = sc[l + 1];
    const float* vp0 = vb + (size_t)l * D_;
    const float* vp1 = vp0 + D_;
    a0a = fmaf(p0, vp0[tid], a0a);
    a1a = fmaf(p0, vp0[tid + 256], a1a);
    a0b = fmaf(p1, vp1[tid], a0b);
    a1b = fmaf(p1, vp1[tid + 256], a1b);
  }
  float* orow = out + ((size_t)b * L_ + l_sel) * D_;
  orow[tid] = (a0a + a0b) * inv;
  orow[tid + 256] = (a1a + a1b) * inv;
}

// ======================= launcher =======================

extern "C" void kernel_launch(void* const* d_in, const int* in_sizes, int n_in,
                              void* d_out, int out_size, void* d_ws, size_t ws_size,
                              hipStream_t stream) {
  const float* q = (const float*)d_in[0];
  const float* k = (const float*)d_in[1];
  const float* v = (const float*)d_in[2];
  float* out = (float*)d_out;
  unsigned char* wsb = (unsigned char*)d_ws;

  const size_t NEED = 71731200;  // fast-path ws bytes

  if (ws_size >= NEED) {
    // ---- fast path ----
    unsigned char* qhiW = wsb;                       // 33554432
    unsigned char* qloW = wsb + 33554432;            // 33554432
    float* P = (float*)wsb;                          // 5373952  (after kRowMaxB)
    float* partial = (float*)(wsb + 5373952);        // 10747904
    unsigned char* qselhi = wsb + 16121856;          // 524288
    unsigned char* qsello = wsb + 16646144;          // 524288
    float* pmax = (float*)(wsb + 67108864);          // 262144
    float* qdot = (float*)(wsb + 67371008);          // 131072
    float* ksum = (float*)(wsb + 67502080);          // 16384
    float* vmean = (float*)(wsb + 67518464);         // 16384
    int* tidx = (int*)(wsb + 67534848);              // 2048
    float* partk = (float*)(wsb + 67536896);         // 2097152 (128 partials/b)
    float* partv = (float*)(wsb + 69634048);         // 2097152 -> 71731200
    // qdotp (8 planes, 1 MB) aliases partk (dead after kSums2V)
    float* qdotp = partk;

    unsigned char* khiO = (unsigned char*)d_out;
    unsigned char* kloO = khiO + 33554432;

    kSumKV<<<dim3(32, B_), 256, 0, stream>>>(k, v, khiO, kloO, partk, partv);
    kSums2V<<<B_, 512, 0, stream>>>(partk, partv, ksum, vmean);
    kConvertQdot<<<8192, 256, 0, stream>>>(q, ksum, qhiW, qloW, qdotp);
    kQdotReduce<<<B_ * L_ / 256, 256, 0, stream>>>(qdotp, qdot);
    kRowMaxB<<<dim3(32, B_, 2), 256, 0, stream>>>(qhiW, qloW, khiO, kloO, pmax);
    kTopK4<<<B_, 64, 0, stream>>>(pmax, qdot, tidx);
    kGatherQ<<<dim3(64, B_), 64, 0, stream>>>(q, tidx, qselhi, qsello);
    kSelScoresM<<<dim3(32, B_), 256, 0, stream>>>(qselhi, qsello, khiO, kloO, P);
    kSoftmaxP<<<dim3(U_, B_), 256, 0, stream>>>(P);
    kFill<<<B_ * L_ * D_ / 1024, 256, 0, stream>>>(vmean, out);
    kPV<<<dim3(8, 4, B_), 256, 0, stream>>>(P, v, partial);
    kPVout<<<dim3(U_, B_), 256, 0, stream>>>(partial, tidx, out);
  } else {
    // ---- fallback: round-2 verified path ----
    float* ws = (float*)d_ws;
    float* Marr = ws;
    float* pmax = ws + 32768;
    float* ksum = ws + 98304;
    float* vmean = ws + 102400;
    int* tidx = (int*)(ws + 106496);
    float* partk = ws + 107008;
    float* partv = ws + 107008 + B_ * NSL * D_;

    kSums1<<<dim3(NSL, B_), 512, 0, stream>>>(k, v, partk, partv);
    kSums2<<<B_, 512, 0, stream>>>(partk, partv, ksum, vmean);
    kRowMaxM<<<dim3(L_ / 128, B_, 2), 256, 0, stream>>>(q, k, pmax);
    kMeanM<<<B_ * L_ / 256, 256, 0, stream>>>(q, ksum, pmax, Marr);
    kTopK3<<<B_, 256, 0, stream>>>(Marr, tidx);
    kFill<<<B_ * L_ * D_ / 1024, 256, 0, stream>>>(vmean, out);
    kAttnSel<<<dim3(U_, B_), 256, 0, stream>>>(q, k, v, tidx, out);
  }
}